// Round 13
// baseline (46.921 us; speedup 1.0000x reference)
//
#include <hip/hip_runtime.h>
#include <math.h>

// RegimeFeatureExtractor: prices [B, T] f32 -> features [B, T, 6] f32
// R12 = R10 (best validated, 42.3 µs) + EDGE templating only.
//   - R10 core: per-thread register-resident 28-float window [tf-24, tf+3]
//     via 7 coalesced f32x4 loads; logs/returns/window sums/bipower fully in
//     registers; LDS only for the swizzled b128 output transpose; coalesced
//     dwordx4 stores; non-persistent 8192-block dispatch.
//   - R11's launch_bounds(256,5) VGPR cap (forced spills, +3.6 µs) and
//     mid-loop fb flush are REVERTED. EDGE split kept: fast path (all but 6
//     lanes of chunk-0 blocks) has zero runtime t-conditionals.
// Math identical to validated R3..R10 (absmax 128): fast log2/rcp/sqrt,
// ln2 folded into the epilogue.

constexpr int BLOCK = 256;
constexpr int RPT   = 4;               // outputs per thread
constexpr int CHUNK = BLOCK * RPT;     // 1024 t per block
constexpr int LDSF  = CHUNK * 6;       // 6144 floats = 24.6 KB (output image)
constexpr float EPS = 1e-8f;
constexpr float LN2 = 0.6931471805599453f;
constexpr float PI_HALF_L2SQ = 1.5707963267948966f * LN2 * LN2;  // bv scale (log2 units)

typedef float f32x4 __attribute__((ext_vector_type(4)));

__device__ __forceinline__ float frcp(float x)  { return __builtin_amdgcn_rcpf(x); }
__device__ __forceinline__ float fsq(float x)   { return __builtin_amdgcn_sqrtf(x); }
__device__ __forceinline__ float flog2(float x) { return __builtin_amdgcn_logf(x); }

template<bool EDGE>
__device__ __forceinline__ void compute_body(const float* __restrict__ pr,
                                             int tf, int tid, f32x4* ost4) {
    // --- 7 coalesced f32x4 loads cover [tf-24, tf+3]; element j -> g = tf-24+j ---
    f32x4 L[7];
    if constexpr (!EDGE) {
        const f32x4* __restrict__ src = (const f32x4*)(pr + (tf - 24));
        #pragma unroll
        for (int m = 0; m < 7; ++m) L[m] = src[m];
    } else {                            // chunk 0, tid < 6: clamped scalar fill
        #pragma unroll
        for (int m = 0; m < 7; ++m)
            #pragma unroll
            for (int e = 0; e < 4; ++e) {
                int g = tf - 24 + 4 * m + e;
                float v = pr[g > 0 ? g : 0];
                L[m][e] = (g >= 0) ? v : 0.0f;   // p = 0 for g < 0 (ref zero-pad)
            }
    }
    const float p0row = EDGE ? pr[0] : 0.0f;     // only used when t < 5

    // ---- single register stream j=4..27 (i = 24-j = 20..-3): sums + bipower ----
    float s5 = 0.f, q5 = 0.f, ps5 = 0.f;
    float s10 = 0.f, q10 = 0.f;
    float s20 = 0.f, q20 = 0.f, ps20 = 0.f;
    float A = 0.f, aprev = 0.f;
    float aA = 0.f, aB = 0.f, aprev20 = 0.f;
    float p0 = 0.f, p5v = 0.f;
    float r10s[3], vnr[3], vnp[3];
    float2 s5s[3], s20s[3];

    float lp_prev = flog2(L[0][3] + EPS);   // j=3: g = tf-21
    #pragma unroll
    for (int j = 4; j < 28; ++j) {
        float p  = L[j >> 2][j & 3];
        float lp = flog2(p + EPS);
        float r  = lp - lp_prev;            // log2 units; ln2 folded at epilogue
        lp_prev = lp;
        if constexpr (EDGE) {
            if ((tf - 24 + j) < 1) r = 0.0f;     // r = 0 for g < 1 (ref pad)
        }
        float a = fabsf(r);
        const int i = 24 - j;               // distance from tf (neg = future k)
        if (i == 20) { aprev20 = a; aprev = a; }
        else if (i >= 1) { A = fmaf(aprev, a, A); aprev = a; }  // pairs to (tf-2,tf-1)
        if (i == 1) aA = a;                 // |r_{tf-1}|
        if (i == 0) aB = a;                 // |r_{tf}|
        if (i >= 7  && i <= 9)  r10s[9 - i]  = r;
        if (i >= 2  && i <= 4)  s5s[4 - i]   = make_float2(r, p);
        if (i >= 17 && i <= 19) s20s[19 - i] = make_float2(r, p);
        if (i <= -1) { vnr[-i - 1] = r; vnp[-i - 1] = p; }      // slide feed k=1..3
        if (i >= 0 && i <= 19) {
            s20 += r; q20 = fmaf(r, r, q20); ps20 += p;
            if (i == 5) p5v = p;
            if (i == 0) p0 = p;
            if (i <= 9) { s10 += r; q10 = fmaf(r, r, q10); }
            if (i <= 4) { s5 += r; q5 = fmaf(r, r, q5); ps5 += p; }
        }
    }

    float fb[RPT * 6];                      // constant-indexed -> VGPRs
    float pt = p0, shifted = p5v;

    #pragma unroll
    for (int k = 0; k < RPT; ++k) {
        if (k > 0) {
            // slide t-1 -> t, fully from registers
            float rn   = vnr[k - 1];
            float r5o  = s5s[k - 1].x;
            float r10o = r10s[k - 1];
            float2 v20 = s20s[k - 1];
            float rn2 = rn * rn;
            s5  += rn - r5o;    q5  += rn2 - r5o  * r5o;
            s10 += rn - r10o;   q10 += rn2 - r10o * r10o;
            s20 += rn - v20.x;  q20 += rn2 - v20.x * v20.x;
            pt      = vnp[k - 1];
            shifted = s5s[k - 1].y;
            ps5  += pt - shifted;
            ps20 += pt - v20.y;
            A = fmaf(aA, aB, A);                 // add pair (t-2, t-1)
            float a20n = fabsf(v20.x);
            A = fmaf(-aprev20, a20n, A);         // drop pair (t-21, t-20)
            aprev20 = a20n;
            aA = aB; aB = fabsf(rn);
        }

        float c5r, c10r, c20r, d5r, d10r, d20r;
        if constexpr (!EDGE) {
            c5r = 0.2f; c10r = 0.1f; c20r = 0.05f;
            d5r = 0.25f; d10r = 1.f / 9.f; d20r = 1.f / 19.f;
        } else {
            const int t = tf + k;
            if (t >= 19) {
                c5r = 0.2f; c10r = 0.1f; c20r = 0.05f;
                d5r = 0.25f; d10r = 1.f / 9.f; d20r = 1.f / 19.f;
            } else {
                int tp1 = t + 1;
                float c5  = (float)(tp1 < 5  ? tp1 : 5);
                float c10 = (float)(tp1 < 10 ? tp1 : 10);
                float c20 = (float)tp1;          // t < 19 -> tp1 <= 19 < 20
                c5r  = frcp(c5);  c10r = frcp(c10);  c20r = frcp(c20);
                d5r  = frcp(fmaxf(c5  - 1.f, 1.f));
                d10r = frcp(fmaxf(c10 - 1.f, 1.f));
                d20r = frcp(fmaxf(c20 - 1.f, 1.f));
            }
        }

        // vars in log2 units; multiply std by ln2 to recover ln-scaled features
        float var5  = (q5  - s5  * s5  * c5r ) * d5r;
        float var10 = (q10 - s10 * s10 * c10r) * d10r;
        float var20 = (q20 - s20 * s20 * c20r) * d20r;
        float std5  = fsq(fmaxf(var5,  0.f)) * LN2;
        float std10 = fsq(fmaxf(var10, 0.f)) * LN2;
        float std20 = fsq(fmaxf(var20, 0.f)) * LN2;
        float f1 = std5, f2 = std10, f3 = std20;
        if constexpr (EDGE) {
            const bool has2 = (tf + k >= 1);
            f1 = has2 ? std5  : 1e-6f;
            f2 = has2 ? std10 : 1e-6f;
            f3 = has2 ? std20 : 1e-6f;
        }

        float m5  = ps5  * c5r;
        float m20 = ps20 * c20r;
        float f4 = (m5 - m20) * frcp(m20 + EPS);

        float sh = shifted;
        if constexpr (EDGE) sh = (tf + k >= 5) ? shifted : p0row;
        float f5 = (pt - sh) * frcp(sh + EPS);

        float rvv = f3 * f3;                     // ln-scaled rv
        float bv = A * PI_HALF_L2SQ;             // ln2^2-scaled bipower
        if constexpr (EDGE) bv = (tf + k >= 20) ? bv : 0.f;
        float f6 = rvv * frcp(bv + EPS);

        fb[k * 6 + 0] = f1; fb[k * 6 + 1] = f2; fb[k * 6 + 2] = f3;
        fb[k * 6 + 3] = f4; fb[k * 6 + 4] = f5; fb[k * 6 + 5] = f6;
    }

    // --- swizzled output image in LDS (validated R7/R10 transpose) ---
    #pragma unroll
    for (int m = 0; m < 6; ++m) {          // granule g = 6*tid+m, swizzled slot
        int g = 6 * tid + m;
        int p = g ^ ((g >> 3) & 7);
        f32x4 v = { fb[4 * m], fb[4 * m + 1], fb[4 * m + 2], fb[4 * m + 3] };
        ost4[p] = v;
    }
}

__global__ __launch_bounds__(BLOCK, 4)
void regime_kernel(const float* __restrict__ prices, float* __restrict__ out, int T) {
    __shared__ __align__(16) float lds[LDSF];
    f32x4* const ost4 = (f32x4*)lds;

    const int tid = threadIdx.x;
    const int t0  = blockIdx.x * CHUNK;
    const int row = blockIdx.y;
    const float* __restrict__ pr = prices + (size_t)row * T;
    const int tf = t0 + tid * RPT;         // first t of this thread

    if (tf >= 24) compute_body<false>(pr, tf, tid, ost4);
    else          compute_body<true >(pr, tf, tid, ost4);

    __syncthreads();

    // --- coalesced stores: 6x dwordx4 (1 KB/wave-instr), through L2 ---
    f32x4* __restrict__ outp4 = (f32x4*)(out + ((size_t)row * T + t0) * 6);
    #pragma unroll
    for (int r = 0; r < 6; ++r) {
        int g = r * BLOCK + tid;
        int p = g ^ ((g >> 3) & 7);
        outp4[g] = ost4[p];
    }
}

extern "C" void kernel_launch(void* const* d_in, const int* in_sizes, int n_in,
                              void* d_out, int out_size, void* d_ws, size_t ws_size,
                              hipStream_t stream) {
    const float* prices = (const float*)d_in[0];
    float* out = (float*)d_out;
    const int T = 8192;                 // per reference setup_inputs()
    const int B = in_sizes[0] / T;      // 1024
    dim3 grid(T / CHUNK, B);
    hipLaunchKernelGGL(regime_kernel, grid, dim3(BLOCK), 0, stream, prices, out, T);
}

// Round 14
// 42.209 us; speedup vs baseline: 1.1116x; 1.1116x over previous
//
#include <hip/hip_runtime.h>
#include <math.h>

// RegimeFeatureExtractor: prices [B, T] f32 -> features [B, T, 6] f32
// R13 = R10 verbatim (best validated: 42.3 µs). R11 (VGPR cap -> spills) and
// R12 (template<EDGE> split -> divergent dual-body codegen, rule-#19 effect)
// both regressed; compute-side slack is fully hidden under the mixed HBM
// stream, so the R10 structure is the optimum found:
//   - per-thread register-resident 28-float window [tf-24, tf+3] via 7
//     coalesced f32x4 loads (lane-contiguous 1KB wave-reads, L1-absorbed);
//   - logs/returns/window sums/bipower entirely in registers, runtime
//     t-conditionals (uniform, hidden);
//   - LDS only for the swizzled b128 output transpose; coalesced dwordx4
//     stores; non-persistent 8192-block dispatch (persistence caused RMW).
// Math: fast log2/rcp/sqrt, ln2 folded at epilogue (absmax 128, thr 1203).

constexpr int BLOCK = 256;
constexpr int RPT   = 4;               // outputs per thread
constexpr int CHUNK = BLOCK * RPT;     // 1024 t per block
constexpr int LDSF  = CHUNK * 6;       // 6144 floats = 24.6 KB (output image)
constexpr float EPS = 1e-8f;
constexpr float LN2 = 0.6931471805599453f;
constexpr float PI_HALF_L2SQ = 1.5707963267948966f * LN2 * LN2;  // bv scale (log2 units)

typedef float f32x4 __attribute__((ext_vector_type(4)));

__device__ __forceinline__ float frcp(float x)  { return __builtin_amdgcn_rcpf(x); }
__device__ __forceinline__ float fsq(float x)   { return __builtin_amdgcn_sqrtf(x); }
__device__ __forceinline__ float flog2(float x) { return __builtin_amdgcn_logf(x); }

__global__ __launch_bounds__(BLOCK, 4)
void regime_kernel(const float* __restrict__ prices, float* __restrict__ out, int T) {
    __shared__ __align__(16) float lds[LDSF];
    f32x4* const ost4 = (f32x4*)lds;

    const int tid = threadIdx.x;
    const int t0  = blockIdx.x * CHUNK;
    const int row = blockIdx.y;
    const float* __restrict__ pr = prices + (size_t)row * T;

    const int tf = t0 + tid * RPT;         // first t of this thread
    const float p0row = pr[0];             // uniform; only used when t < 5

    // --- 7 coalesced f32x4 loads cover [tf-24, tf+3]; element j -> g = tf-24+j ---
    f32x4 L[7];
    if (tf >= 24) {
        const f32x4* __restrict__ src = (const f32x4*)(pr + (tf - 24));
        #pragma unroll
        for (int m = 0; m < 7; ++m) L[m] = src[m];
    } else {                                // chunk 0, tid < 6: clamped scalar fill
        #pragma unroll
        for (int m = 0; m < 7; ++m)
            #pragma unroll
            for (int e = 0; e < 4; ++e) {
                int g = tf - 24 + 4 * m + e;
                float v = pr[g > 0 ? g : 0];
                L[m][e] = (g >= 0) ? v : 0.0f;   // p = 0 for g < 0 (ref zero-pad)
            }
    }

    // ---- single register stream j=4..27 (i = 24-j = 20..-3): sums + bipower ----
    float s5 = 0.f, q5 = 0.f, ps5 = 0.f;
    float s10 = 0.f, q10 = 0.f;
    float s20 = 0.f, q20 = 0.f, ps20 = 0.f;
    float A = 0.f, aprev = 0.f;
    float aA = 0.f, aB = 0.f, aprev20 = 0.f;
    float p0 = 0.f, p5v = 0.f;
    float r10s[3], vnr[3], vnp[3];
    float2 s5s[3], s20s[3];

    float lp_prev = flog2(L[0][3] + EPS);   // j=3: g = tf-21
    #pragma unroll
    for (int j = 4; j < 28; ++j) {
        float p  = L[j >> 2][j & 3];
        float lp = flog2(p + EPS);
        float r  = lp - lp_prev;            // log2 units; ln2 folded at epilogue
        lp_prev = lp;
        if (tf < 24 && (tf - 24 + j) < 1) r = 0.0f;   // r = 0 for g < 1 (ref pad)
        float a = fabsf(r);
        const int i = 24 - j;               // distance from tf (neg = future k)
        if (i == 20) { aprev20 = a; aprev = a; }
        else if (i >= 1) { A = fmaf(aprev, a, A); aprev = a; }  // pairs to (tf-2,tf-1)
        if (i == 1) aA = a;                 // |r_{tf-1}|
        if (i == 0) aB = a;                 // |r_{tf}|
        if (i >= 7  && i <= 9)  r10s[9 - i]  = r;
        if (i >= 2  && i <= 4)  s5s[4 - i]   = make_float2(r, p);
        if (i >= 17 && i <= 19) s20s[19 - i] = make_float2(r, p);
        if (i <= -1) { vnr[-i - 1] = r; vnp[-i - 1] = p; }      // slide feed k=1..3
        if (i >= 0 && i <= 19) {
            s20 += r; q20 = fmaf(r, r, q20); ps20 += p;
            if (i == 5) p5v = p;
            if (i == 0) p0 = p;
            if (i <= 9) { s10 += r; q10 = fmaf(r, r, q10); }
            if (i <= 4) { s5 += r; q5 = fmaf(r, r, q5); ps5 += p; }
        }
    }

    float fb[RPT * 6];                      // constant-indexed -> VGPRs
    float pt = p0, shifted = p5v;

    #pragma unroll
    for (int k = 0; k < RPT; ++k) {
        const int t = tf + k;
        if (k > 0) {
            // slide t-1 -> t, fully from registers
            float rn   = vnr[k - 1];
            float r5o  = s5s[k - 1].x;
            float r10o = r10s[k - 1];
            float2 v20 = s20s[k - 1];
            float rn2 = rn * rn;
            s5  += rn - r5o;    q5  += rn2 - r5o  * r5o;
            s10 += rn - r10o;   q10 += rn2 - r10o * r10o;
            s20 += rn - v20.x;  q20 += rn2 - v20.x * v20.x;
            pt      = vnp[k - 1];
            shifted = s5s[k - 1].y;
            ps5  += pt - shifted;
            ps20 += pt - v20.y;
            A = fmaf(aA, aB, A);                 // add pair (t-2, t-1)
            float a20n = fabsf(v20.x);
            A = fmaf(-aprev20, a20n, A);         // drop pair (t-21, t-20)
            aprev20 = a20n;
            aA = aB; aB = fabsf(rn);
        }

        float c5r, c10r, c20r, d5r, d10r, d20r;
        if (t >= 19) {
            c5r = 0.2f; c10r = 0.1f; c20r = 0.05f;
            d5r = 0.25f; d10r = 1.f / 9.f; d20r = 1.f / 19.f;
        } else {
            int tp1 = t + 1;
            float c5  = (float)(tp1 < 5  ? tp1 : 5);
            float c10 = (float)(tp1 < 10 ? tp1 : 10);
            float c20 = (float)tp1;              // t < 19 -> tp1 <= 19 < 20
            c5r  = frcp(c5);  c10r = frcp(c10);  c20r = frcp(c20);
            d5r  = frcp(fmaxf(c5  - 1.f, 1.f));
            d10r = frcp(fmaxf(c10 - 1.f, 1.f));
            d20r = frcp(fmaxf(c20 - 1.f, 1.f));
        }

        // vars in log2 units; multiply std by ln2 to recover ln-scaled features
        float var5  = (q5  - s5  * s5  * c5r ) * d5r;
        float var10 = (q10 - s10 * s10 * c10r) * d10r;
        float var20 = (q20 - s20 * s20 * c20r) * d20r;
        float std5  = fsq(fmaxf(var5,  0.f)) * LN2;
        float std10 = fsq(fmaxf(var10, 0.f)) * LN2;
        float std20 = fsq(fmaxf(var20, 0.f)) * LN2;
        const bool has2 = (t >= 1);
        float f1 = has2 ? std5  : 1e-6f;
        float f2 = has2 ? std10 : 1e-6f;
        float f3 = has2 ? std20 : 1e-6f;

        float m5  = ps5  * c5r;
        float m20 = ps20 * c20r;
        float f4 = (m5 - m20) * frcp(m20 + EPS);

        float sh = (t >= 5) ? shifted : p0row;
        float f5 = (pt - sh) * frcp(sh + EPS);

        float rvv = f3 * f3;                       // ln-scaled rv
        float bv = (t >= 20) ? A * PI_HALF_L2SQ : 0.f;  // ln2^2-scaled bipower
        float f6 = rvv * frcp(bv + EPS);

        fb[k * 6 + 0] = f1; fb[k * 6 + 1] = f2; fb[k * 6 + 2] = f3;
        fb[k * 6 + 3] = f4; fb[k * 6 + 4] = f5; fb[k * 6 + 5] = f6;
    }

    // --- swizzled output image in LDS (validated R7 transpose) ---
    #pragma unroll
    for (int m = 0; m < 6; ++m) {          // granule g = 6*tid+m, swizzled slot
        int g = 6 * tid + m;
        int p = g ^ ((g >> 3) & 7);
        f32x4 v = { fb[4 * m], fb[4 * m + 1], fb[4 * m + 2], fb[4 * m + 3] };
        ost4[p] = v;
    }
    __syncthreads();

    // --- coalesced stores: 6x dwordx4 (1 KB/wave-instr), through L2 ---
    f32x4* __restrict__ outp4 = (f32x4*)(out + ((size_t)row * T + t0) * 6);
    #pragma unroll
    for (int r = 0; r < 6; ++r) {
        int g = r * BLOCK + tid;
        int p = g ^ ((g >> 3) & 7);
        outp4[g] = ost4[p];
    }
}

extern "C" void kernel_launch(void* const* d_in, const int* in_sizes, int n_in,
                              void* d_out, int out_size, void* d_ws, size_t ws_size,
                              hipStream_t stream) {
    const float* prices = (const float*)d_in[0];
    float* out = (float*)d_out;
    const int T = 8192;                 // per reference setup_inputs()
    const int B = in_sizes[0] / T;      // 1024
    dim3 grid(T / CHUNK, B);
    hipLaunchKernelGGL(regime_kernel, grid, dim3(BLOCK), 0, stream, prices, out, T);
}